// Round 1
// baseline (2901.754 us; speedup 1.0000x reference)
//
#include <hip/hip_runtime.h>

#define NN 50000
#define NE 800000
#define HD 128

// ---------------- degree / normalization ----------------

__global__ void k_deg_init(float* __restrict__ deg) {
    int i = blockIdx.x * 256 + threadIdx.x;
    if (i < NN) deg[i] = 1.0f;  // self-loop contributes 1
}

__global__ void k_deg_count(const int* __restrict__ row, float* __restrict__ deg) {
    int e = blockIdx.x * 256 + threadIdx.x;
    if (e < NE) atomicAdd(&deg[row[e]], 1.0f);
}

__global__ void k_dinv(float* __restrict__ deg) {
    int i = blockIdx.x * 256 + threadIdx.x;
    if (i < NN) deg[i] = rsqrtf(deg[i]);  // deg >= 1 always
}

// ---------------- aggregation: dst = Dinv A Dinv src  (A includes self-loops) --------

// self-loop term, fully overwrites dst (required: ws/d_out re-poisoned each call)
__global__ void k_agg_init(const float* __restrict__ src, const float* __restrict__ dinv,
                           float* __restrict__ dst) {
    int idx = blockIdx.x * 256 + threadIdx.x;  // float4 index, total NN*HD/4
    if (idx >= NN * (HD / 4)) return;
    int node = idx >> 5;  // 32 float4 per node row
    float d = dinv[node];
    float s = d * d;
    float4 v = ((const float4*)src)[idx];
    ((float4*)dst)[idx] = make_float4(v.x * s, v.y * s, v.z * s, v.w * s);
}

// one edge per 32 lanes; float4 per lane; coalesced 512B gather + scatter-atomics
__global__ void k_agg_edges(const float* __restrict__ src, const int* __restrict__ ei,
                            const float* __restrict__ dinv, float* __restrict__ dst) {
    int t = blockIdx.x * 256 + threadIdx.x;
    int e = t >> 5;
    if (e >= NE) return;
    int f4 = t & 31;
    int r = ei[e];        // destination (segment id)
    int c = ei[NE + e];   // source (gather)
    float w = dinv[r] * dinv[c];
    float4 v = ((const float4*)(src + (size_t)c * HD))[f4];
    float* o = dst + (size_t)r * HD + f4 * 4;
    atomicAdd(o + 0, w * v.x);
    atomicAdd(o + 1, w * v.y);
    atomicAdd(o + 2, w * v.z);
    atomicAdd(o + 3, w * v.w);
}

// ---------------- fp32 GEMM: C[nrows,128] = act(A[nrows,128] @ W[128,128] + b) -------
// block: 128 rows x 128 cols, 256 threads; thread = 4 rows x 16 cols
// LDS: W 64KB + A-tile 16KB (XOR-swizzled) = 80KB -> 2 blocks/CU

template <bool RELU>
__global__ __launch_bounds__(256, 2) void k_gemm(const float* __restrict__ A,
                                                 const float* __restrict__ W,
                                                 const float* __restrict__ bias,
                                                 float* __restrict__ C, int nrows) {
    __shared__ float Ws[128][128];
    __shared__ float As[128][32];  // float4-granular XOR swizzle on column
    int t = threadIdx.x;

    // stage W: 4096 float4, 16 per thread, coalesced
    const float4* W4 = (const float4*)W;
#pragma unroll
    for (int u = 0; u < 16; ++u) {
        int i4 = u * 256 + t;
        ((float4*)Ws)[i4] = W4[i4];
    }

    int row0 = blockIdx.x * 128;
    int tx = t & 7;    // column group: cols tx*4 + i*32 + j
    int ty = t >> 3;   // row group: rows ty*4 + m

    float acc[4][16];
#pragma unroll
    for (int m = 0; m < 4; ++m)
#pragma unroll
        for (int j = 0; j < 16; ++j) acc[m][j] = 0.0f;

    for (int kb = 0; kb < 4; ++kb) {
        __syncthreads();
        // stage A tile rows row0..+127, k = kb*32..+31
#pragma unroll
        for (int u = 0; u < 4; ++u) {
            int i4 = u * 256 + t;      // 0..1023
            int r = i4 >> 3;           // 8 float4 per row
            int uc = i4 & 7;
            float4 v = make_float4(0.f, 0.f, 0.f, 0.f);
            int gr = row0 + r;
            if (gr < nrows) v = *(const float4*)(A + (size_t)gr * HD + kb * 32 + uc * 4);
            int us = uc ^ ((r >> 2) & 7);  // swizzle: bank-conflict-free reads
            *(float4*)&As[r][us * 4] = v;
        }
        __syncthreads();
#pragma unroll
        for (int kk = 0; kk < 32; ++kk) {
            int hi = kk >> 2, lo = kk & 3;
            float a[4];
#pragma unroll
            for (int m = 0; m < 4; ++m) {
                int r = ty * 4 + m;
                a[m] = As[r][(((hi ^ ((r >> 2) & 7)) << 2) | lo)];
            }
#pragma unroll
            for (int i = 0; i < 4; ++i) {
                float4 w = *(const float4*)&Ws[kb * 32 + kk][tx * 4 + i * 32];
#pragma unroll
                for (int m = 0; m < 4; ++m) {
                    acc[m][i * 4 + 0] = fmaf(a[m], w.x, acc[m][i * 4 + 0]);
                    acc[m][i * 4 + 1] = fmaf(a[m], w.y, acc[m][i * 4 + 1]);
                    acc[m][i * 4 + 2] = fmaf(a[m], w.z, acc[m][i * 4 + 2]);
                    acc[m][i * 4 + 3] = fmaf(a[m], w.w, acc[m][i * 4 + 3]);
                }
            }
        }
    }

#pragma unroll
    for (int m = 0; m < 4; ++m) {
        int gr = row0 + ty * 4 + m;
        if (gr >= nrows) continue;
#pragma unroll
        for (int i = 0; i < 4; ++i) {
            int cb = tx * 4 + i * 32;
            float4 b4 = *(const float4*)(bias + cb);
            float4 o;
            o.x = acc[m][i * 4 + 0] + b4.x;
            o.y = acc[m][i * 4 + 1] + b4.y;
            o.z = acc[m][i * 4 + 2] + b4.z;
            o.w = acc[m][i * 4 + 3] + b4.w;
            if (RELU) {
                o.x = fmaxf(o.x, 0.f);
                o.y = fmaxf(o.y, 0.f);
                o.z = fmaxf(o.z, 0.f);
                o.w = fmaxf(o.w, 0.f);
            }
            *(float4*)(C + (size_t)gr * HD + cb) = o;
        }
    }
}

// ---------------- launch ----------------
// math: out = Dhat (x) @ W1 ... using agg(x)@W == agg(x@W) (linearity), so:
//   t1 = agg(x);        h  = relu(t1@W1 + b1)   -> stored in d_out (reused as temp)
//   t1 = agg(h);        out= t1@W2 + b2         -> d_out (final, written once)

extern "C" void kernel_launch(void* const* d_in, const int* in_sizes, int n_in,
                              void* d_out, int out_size, void* d_ws, size_t ws_size,
                              hipStream_t stream) {
    const float* x  = (const float*)d_in[0];
    const int*   ei = (const int*)d_in[1];
    const float* W1 = (const float*)d_in[2];
    const float* b1 = (const float*)d_in[3];
    const float* W2 = (const float*)d_in[4];
    const float* b2 = (const float*)d_in[5];
    float* out = (float*)d_out;

    char* ws = (char*)d_ws;
    float* dinv = (float*)ws;                 // NN floats (~200KB), reused in place
    float* t1   = (float*)(ws + (1 << 18));   // NN*HD floats (25.6MB)

    // normalization
    k_deg_init<<<(NN + 255) / 256, 256, 0, stream>>>(dinv);
    k_deg_count<<<(NE + 255) / 256, 256, 0, stream>>>(ei, dinv);
    k_dinv<<<(NN + 255) / 256, 256, 0, stream>>>(dinv);

    // conv1
    k_agg_init<<<(NN * (HD / 4) + 255) / 256, 256, 0, stream>>>(x, dinv, t1);
    k_agg_edges<<<(NE * 32 + 255) / 256, 256, 0, stream>>>(x, ei, dinv, t1);
    k_gemm<true><<<(NN + 127) / 128, 256, 0, stream>>>(t1, W1, b1, out, NN);

    // conv2 (out currently holds hidden h; consumed before being overwritten)
    k_agg_init<<<(NN * (HD / 4) + 255) / 256, 256, 0, stream>>>(out, dinv, t1);
    k_agg_edges<<<(NE * 32 + 255) / 256, 256, 0, stream>>>(out, ei, dinv, t1);
    k_gemm<false><<<(NN + 127) / 128, 256, 0, stream>>>(t1, W2, b2, out, NN);
}

// Round 4
// 389.649 us; speedup vs baseline: 7.4471x; 7.4471x over previous
//
#include <hip/hip_runtime.h>

#define NN 50000
#define NE 800000
#define HD 128
#define NB 196  // ceil(NN/256)

// ---------------- degree histogram ----------------

__global__ void k_zero(int* __restrict__ p, int n) {
    int i = blockIdx.x * 256 + threadIdx.x;
    if (i < n) p[i] = 0;
}

__global__ void k_deg_count(const int* __restrict__ row, int* __restrict__ deg) {
    int e = blockIdx.x * 256 + threadIdx.x;
    if (e < NE) atomicAdd(&deg[row[e]], 1);
}

// ---------------- two-level exclusive scan over deg -> offs ----------------

__global__ void k_scan1(const int* __restrict__ deg, int* __restrict__ offs,
                        int* __restrict__ part) {
    __shared__ int s[256];
    int t = threadIdx.x;
    int i = blockIdx.x * 256 + t;
    int v = (i < NN) ? deg[i] : 0;
    s[t] = v;
    __syncthreads();
#pragma unroll
    for (int off = 1; off < 256; off <<= 1) {
        int x = (t >= off) ? s[t - off] : 0;
        __syncthreads();
        s[t] += x;
        __syncthreads();
    }
    if (i < NN) offs[i] = s[t] - v;  // exclusive within block
    if (t == 255) part[blockIdx.x] = s[255];
}

__global__ void k_scan2(int* __restrict__ part) {
    __shared__ int s[256];
    int t = threadIdx.x;
    int v = (t < NB) ? part[t] : 0;
    s[t] = v;
    __syncthreads();
#pragma unroll
    for (int off = 1; off < 256; off <<= 1) {
        int x = (t >= off) ? s[t - off] : 0;
        __syncthreads();
        s[t] += x;
        __syncthreads();
    }
    if (t < NB) part[t] = s[t] - v;  // exclusive block offsets
}

// add block offsets; also produce cursor copy and dinv
__global__ void k_scan3(int* __restrict__ offs, const int* __restrict__ part,
                        const int* __restrict__ deg, int* __restrict__ cursor,
                        float* __restrict__ dinv) {
    int i = blockIdx.x * 256 + threadIdx.x;
    if (i >= NN) return;
    int o = offs[i] + part[blockIdx.x];
    offs[i] = o;
    cursor[i] = o;
    dinv[i] = rsqrtf((float)(deg[i] + 1));  // +1 self-loop
}

// ---------------- CSR fill: group source indices by destination ----------------

__global__ void k_fill(const int* __restrict__ ei, int* __restrict__ cursor,
                       int* __restrict__ csr) {
    int e = blockIdx.x * 256 + threadIdx.x;
    if (e >= NE) return;
    int r = ei[e];
    int slot = atomicAdd(&cursor[r], 1);
    csr[slot] = ei[NE + e];
}

// ---------------- aggregation: one wave per node, no atomics ----------------
// dst[r] = dinv[r]^2 * src[r] + sum_e dinv[r]*dinv[c_e] * src[c_e]

__global__ __launch_bounds__(256) void k_agg_csr(const float* __restrict__ src,
                                                 const int* __restrict__ csr,
                                                 const int* __restrict__ offs,
                                                 const int* __restrict__ deg,
                                                 const float* __restrict__ dinv,
                                                 float* __restrict__ dst) {
    int node = blockIdx.x * 4 + (threadIdx.x >> 6);  // 4 waves/block, grid exact
    int lane = threadIdx.x & 63;
    int o = offs[node];
    int dg = deg[node];
    float d = dinv[node];

    float2 v = ((const float2*)(src + (size_t)node * HD))[lane];
    float s = d * d;
    float2 acc = make_float2(s * v.x, s * v.y);

    for (int base = 0; base < dg; base += 64) {
        int n = min(64, dg - base);
        int myc = (lane < n) ? csr[o + base + lane] : 0;
        float myw = (lane < n) ? d * dinv[myc] : 0.0f;
        for (int j = 0; j < n; ++j) {
            int c = __shfl(myc, j);
            float w = __shfl(myw, j);
            float2 vv = ((const float2*)(src + (size_t)c * HD))[lane];
            acc.x = fmaf(w, vv.x, acc.x);
            acc.y = fmaf(w, vv.y, acc.y);
        }
    }
    ((float2*)(dst + (size_t)node * HD))[lane] = acc;
}

// ---------------- fp32 GEMM: C[nrows,128] = act(A[nrows,128] @ W[128,128] + b) -------

template <bool RELU>
__global__ __launch_bounds__(256, 2) void k_gemm(const float* __restrict__ A,
                                                 const float* __restrict__ W,
                                                 const float* __restrict__ bias,
                                                 float* __restrict__ C, int nrows) {
    __shared__ float Ws[128][128];
    __shared__ float As[128][32];
    int t = threadIdx.x;

    const float4* W4 = (const float4*)W;
#pragma unroll
    for (int u = 0; u < 16; ++u) {
        int i4 = u * 256 + t;
        ((float4*)Ws)[i4] = W4[i4];
    }

    int row0 = blockIdx.x * 128;
    int tx = t & 7;
    int ty = t >> 3;

    float acc[4][16];
#pragma unroll
    for (int m = 0; m < 4; ++m)
#pragma unroll
        for (int j = 0; j < 16; ++j) acc[m][j] = 0.0f;

    for (int kb = 0; kb < 4; ++kb) {
        __syncthreads();
#pragma unroll
        for (int u = 0; u < 4; ++u) {
            int i4 = u * 256 + t;
            int r = i4 >> 3;
            int uc = i4 & 7;
            float4 v = make_float4(0.f, 0.f, 0.f, 0.f);
            int gr = row0 + r;
            if (gr < nrows) v = *(const float4*)(A + (size_t)gr * HD + kb * 32 + uc * 4);
            int us = uc ^ ((r >> 2) & 7);
            *(float4*)&As[r][us * 4] = v;
        }
        __syncthreads();
#pragma unroll
        for (int kk = 0; kk < 32; ++kk) {
            int hi = kk >> 2, lo = kk & 3;
            float a[4];
#pragma unroll
            for (int m = 0; m < 4; ++m) {
                int r = ty * 4 + m;
                a[m] = As[r][(((hi ^ ((r >> 2) & 7)) << 2) | lo)];
            }
#pragma unroll
            for (int i = 0; i < 4; ++i) {
                float4 w = *(const float4*)&Ws[kb * 32 + kk][tx * 4 + i * 32];
#pragma unroll
                for (int m = 0; m < 4; ++m) {
                    acc[m][i * 4 + 0] = fmaf(a[m], w.x, acc[m][i * 4 + 0]);
                    acc[m][i * 4 + 1] = fmaf(a[m], w.y, acc[m][i * 4 + 1]);
                    acc[m][i * 4 + 2] = fmaf(a[m], w.z, acc[m][i * 4 + 2]);
                    acc[m][i * 4 + 3] = fmaf(a[m], w.w, acc[m][i * 4 + 3]);
                }
            }
        }
    }

#pragma unroll
    for (int m = 0; m < 4; ++m) {
        int gr = row0 + ty * 4 + m;
        if (gr >= nrows) continue;
#pragma unroll
        for (int i = 0; i < 4; ++i) {
            int cb = tx * 4 + i * 32;
            float4 b4 = *(const float4*)(bias + cb);
            float4 o;
            o.x = acc[m][i * 4 + 0] + b4.x;
            o.y = acc[m][i * 4 + 1] + b4.y;
            o.z = acc[m][i * 4 + 2] + b4.z;
            o.w = acc[m][i * 4 + 3] + b4.w;
            if (RELU) {
                o.x = fmaxf(o.x, 0.f);
                o.y = fmaxf(o.y, 0.f);
                o.z = fmaxf(o.z, 0.f);
                o.w = fmaxf(o.w, 0.f);
            }
            *(float4*)(C + (size_t)gr * HD + cb) = o;
        }
    }
}

// ---------------- launch ----------------

extern "C" void kernel_launch(void* const* d_in, const int* in_sizes, int n_in,
                              void* d_out, int out_size, void* d_ws, size_t ws_size,
                              hipStream_t stream) {
    const float* x  = (const float*)d_in[0];
    const int*   ei = (const int*)d_in[1];
    const float* W1 = (const float*)d_in[2];
    const float* b1 = (const float*)d_in[3];
    const float* W2 = (const float*)d_in[4];
    const float* b2 = (const float*)d_in[5];
    float* out = (float*)d_out;

    char* ws = (char*)d_ws;
    size_t off = 0;
    auto alloc = [&](size_t bytes) {
        void* p = ws + off;
        off = (off + bytes + 255) & ~(size_t)255;
        return p;
    };
    int*   deg    = (int*)alloc(NN * 4);
    int*   offs   = (int*)alloc(NN * 4);
    int*   cursor = (int*)alloc(NN * 4);
    int*   part   = (int*)alloc(256 * 4);
    float* dinv   = (float*)alloc(NN * 4);
    int*   csr    = (int*)alloc((size_t)NE * 4);
    float* t1     = (float*)alloc((size_t)NN * HD * 4);

    // CSR build (once per call)
    k_zero<<<NB, 256, 0, stream>>>(deg, NN);
    k_deg_count<<<(NE + 255) / 256, 256, 0, stream>>>(ei, deg);
    k_scan1<<<NB, 256, 0, stream>>>(deg, offs, part);
    k_scan2<<<1, 256, 0, stream>>>(part);
    k_scan3<<<NB, 256, 0, stream>>>(offs, part, deg, cursor, dinv);
    k_fill<<<(NE + 255) / 256, 256, 0, stream>>>(ei, cursor, csr);

    // conv1: t1 = agg(x); out(h) = relu(t1@W1 + b1)
    k_agg_csr<<<NN / 4, 256, 0, stream>>>(x, csr, offs, deg, dinv, t1);
    k_gemm<true><<<(NN + 127) / 128, 256, 0, stream>>>(t1, W1, b1, out, NN);

    // conv2: t1 = agg(h); out = t1@W2 + b2
    k_agg_csr<<<NN / 4, 256, 0, stream>>>(out, csr, offs, deg, dinv, t1);
    k_gemm<false><<<(NN + 127) / 128, 256, 0, stream>>>(t1, W2, b2, out, NN);
}